// Round 2
// baseline (355.528 us; speedup 1.0000x reference)
//
#include <hip/hip_runtime.h>
#include <cstdint>

#define GEPS 1e-6f

typedef __attribute__((ext_vector_type(8))) short bf16x8;
typedef __attribute__((ext_vector_type(4))) float f32x4;

__device__ __forceinline__ unsigned short f2bf(float f) {
  unsigned int u = __float_as_uint(f);
  u += 0x7fffu + ((u >> 16) & 1u);
  return (unsigned short)(u >> 16);
}

__device__ __forceinline__ float bf2f(unsigned short h) {
  return __uint_as_float(((unsigned int)h) << 16);
}

// A&S 7.1.26 erf (|err| <= 1.5e-7) with native rcp/exp2. gelu exact form.
__device__ __forceinline__ float fast_gelu(float x) {
  float z  = x * 0.70710678118654752f;
  float az = fabsf(z);
  float t  = __builtin_amdgcn_rcpf(fmaf(0.3275911f, az, 1.0f));
  float poly = t * fmaf(t, fmaf(t, fmaf(t, fmaf(t, 1.061405429f, -1.453152027f),
                    1.421413741f), -0.284496736f), 0.254829592f);
  float e  = __builtin_amdgcn_exp2f(-az * az * 1.4426950408889634f);
  float ea = fmaf(-poly, e, 1.0f);                       // erf(|z|), >= 0
  float er = __uint_as_float(__float_as_uint(ea) | (__float_as_uint(z) & 0x80000000u));
  return 0.5f * x * (1.0f + er);
}

__device__ __forceinline__ float fast_sigmoid(float s) {
  return __builtin_amdgcn_rcpf(1.0f + __builtin_amdgcn_exp2f(-s * 1.4426950408889634f));
}

__device__ __forceinline__ float fast_log(float x) {
  return __builtin_amdgcn_logf(x) * 0.69314718055994531f;
}

// Pack W1 [C=256][H=256] fp32 -> bf16 fragment-major for the B-operand of
// mfma_f32_16x16x32_bf16: frag (h_tile, kk) is 1 KB; within it lane l=q*16+tl
// holds B[k = kk*32 + q*8 + j][h = h_tile*16 + tl], j=0..7 contiguous.
__global__ void pack_w1(const float* __restrict__ W1, unsigned short* __restrict__ wt) {
  int k = blockIdx.x;    // 0..255 (C)
  int h = threadIdx.x;   // 0..255 (H)
  float v = W1[k * 256 + h];
  int h_tile = h >> 4, tl = h & 15, kk = k >> 5, q = (k >> 3) & 3, j = k & 7;
  wt[(((h_tile << 3) + kk) << 9) + (q << 7) + (tl << 3) + j] = f2bf(v);
}

// 128 threads (2 waves), 32 tokens/block, 4096 blocks. ~19 KB LDS -> 8 blocks/CU.
__global__ __launch_bounds__(128, 4) void gater_main(
    const float* __restrict__ x, const unsigned short* __restrict__ wt,
    const float* __restrict__ b1, const float* __restrict__ w2,
    const float* __restrict__ b2,
    float* __restrict__ y, float* __restrict__ scores, float* __restrict__ probs,
    float* __restrict__ bg_ws, float* __restrict__ sums)
{
  __shared__ short A_lds[32 * 260];     // 32 tokens x 256 K bf16, stride 260 (pad: 130 dw == 2 mod 32)
  __shared__ float sc_lds[2][32];
  __shared__ float p_lds[32];
  __shared__ float bg_lds[2][256];

  const int tid = threadIdx.x;
  const int tok0 = blockIdx.x * 32;     // flat token index (b*N + n)
  const int b = tok0 >> 12;             // N = 4096
  const int n0 = tok0 & 4095;
  const float* xblk = x + (size_t)tok0 * 256;

  // ---- stage x tile fp32 -> bf16 (RTN) into LDS ----
  #pragma unroll
  for (int i = 0; i < 16; ++i) {
    int f = i * 128 + tid;              // float4 index within 32x256 tile
    int token = f >> 6;
    int k4 = (f & 63) << 2;
    const float4 v = *(const float4*)(xblk + (size_t)f * 4);
    unsigned int lo = (unsigned int)f2bf(v.x) | ((unsigned int)f2bf(v.y) << 16);
    unsigned int hi = (unsigned int)f2bf(v.z) | ((unsigned int)f2bf(v.w) << 16);
    *(uint2*)&A_lds[token * 260 + k4] = make_uint2(lo, hi);
  }
  __syncthreads();

  const int wave = tid >> 6, lane = tid & 63, tl = lane & 15, q = lane >> 4;

  f32x4 acc[2][8];
  #pragma unroll
  for (int mi = 0; mi < 2; ++mi)
    #pragma unroll
    for (int ni = 0; ni < 8; ++ni)
      acc[mi][ni] = (f32x4){0.f, 0.f, 0.f, 0.f};

  const bf16x8* wtv = (const bf16x8*)wt;
  #pragma unroll
  for (int kk = 0; kk < 8; ++kk) {
    bf16x8 a[2];
    #pragma unroll
    for (int mi = 0; mi < 2; ++mi)
      a[mi] = *(const bf16x8*)&A_lds[(mi * 16 + tl) * 260 + kk * 32 + q * 8];
    #pragma unroll
    for (int ni = 0; ni < 8; ++ni) {
      bf16x8 bb = wtv[(((wave * 8 + ni) * 8) + kk) * 64 + lane];
      acc[0][ni] = __builtin_amdgcn_mfma_f32_16x16x32_bf16(a[0], bb, acc[0][ni], 0, 0, 0);
      acc[1][ni] = __builtin_amdgcn_mfma_f32_16x16x32_bf16(a[1], bb, acc[1][ni], 0, 0, 0);
    }
  }

  // ---- epilogue: gelu(h + b1) . w2, reduce over this wave's 128 H cols ----
  float w2v[8], b1v[8];
  #pragma unroll
  for (int ni = 0; ni < 8; ++ni) {
    int h = wave * 128 + ni * 16 + tl;
    w2v[ni] = w2[h];
    b1v[ni] = b1[h];
  }
  #pragma unroll
  for (int mi = 0; mi < 2; ++mi) {
    #pragma unroll
    for (int r = 0; r < 4; ++r) {
      float s = 0.f;
      #pragma unroll
      for (int ni = 0; ni < 8; ++ni)
        s += fast_gelu(acc[mi][ni][r] + b1v[ni]) * w2v[ni];
      #pragma unroll
      for (int m = 1; m < 16; m <<= 1) s += __shfl_xor(s, m, 64);
      if (tl == 0) sc_lds[wave][mi * 16 + q * 4 + r] = s;   // token = mi*16 + q*4 + r
    }
  }
  __syncthreads();

  if (tid < 32) {
    float s = sc_lds[0][tid] + sc_lds[1][tid] + b2[0];
    float p = fast_sigmoid(s);
    size_t g = (size_t)tok0 + tid;
    scores[g] = s;
    probs[g] = p;
    p_lds[tid] = p;
    float ent = -(p * fast_log(p + GEPS) + (1.0f - p) * fast_log(1.0f - p + GEPS));
    float sp = p, se = ent;
    #pragma unroll
    for (int m = 1; m < 32; m <<= 1) {
      sp += __shfl_xor(sp, m, 64);
      se += __shfl_xor(se, m, 64);
    }
    if (tid == 0) {
      atomicAdd(&sums[b * 2 + 0], sp);
      atomicAdd(&sums[b * 2 + 1], se);
    }
  }
  __syncthreads();

  // ---- y = x * p from LDS (bf16) + bg partial accumulation ----
  float4 bg = make_float4(0.f, 0.f, 0.f, 0.f);
  #pragma unroll
  for (int i = 0; i < 16; ++i) {
    int f = i * 128 + tid;
    int token = f >> 6;
    int k4 = (f & 63) << 2;
    uint2 raw = *(const uint2*)&A_lds[token * 260 + k4];
    float4 xv = make_float4(bf2f((unsigned short)(raw.x & 0xffffu)),
                            bf2f((unsigned short)(raw.x >> 16)),
                            bf2f((unsigned short)(raw.y & 0xffffu)),
                            bf2f((unsigned short)(raw.y >> 16)));
    float p = p_lds[token];
    size_t row = (size_t)b * 4097 + (size_t)(n0 + token);
    *(float4*)(y + row * 256 + k4) =
        make_float4(xv.x * p, xv.y * p, xv.z * p, xv.w * p);
    float bw = 1.0f - p;
    bg.x += xv.x * bw; bg.y += xv.y * bw; bg.z += xv.z * bw; bg.w += xv.w * bw;
  }
  *(float4*)&bg_lds[tid >> 6][(tid & 63) << 2] = bg;
  __syncthreads();
  if (tid < 64) {
    int c = tid << 2;
    float4 v0 = *(const float4*)&bg_lds[0][c];
    float4 v1 = *(const float4*)&bg_lds[1][c];
    atomicAdd(&bg_ws[b * 256 + c + 0], v0.x + v1.x);
    atomicAdd(&bg_ws[b * 256 + c + 1], v0.y + v1.y);
    atomicAdd(&bg_ws[b * 256 + c + 2], v0.z + v1.z);
    atomicAdd(&bg_ws[b * 256 + c + 3], v0.w + v1.w);
  }
}

__global__ void finalize(const float* __restrict__ bg_ws, const float* __restrict__ sums,
                         const int* __restrict__ kp, float* __restrict__ y,
                         float* __restrict__ aux)
{
  int b = blockIdx.x, c = threadIdx.x;
  float sp = sums[b * 2 + 0];
  float denom = fmaxf(4096.0f - sp, GEPS);
  y[((size_t)b * 4097 + 4096) * 256 + c] = bg_ws[b * 256 + c] / denom;
  if (b == 0 && c == 0) {
    float t = (float)kp[0] / 4096.0f;
    float lr = 0.f, le = 0.f;
    for (int i = 0; i < 32; ++i) {
      float r = sums[i * 2 + 0] / 4096.0f;
      lr += (r - t) * (r - t);
      le += sums[i * 2 + 1];
    }
    aux[0] = lr / 32.0f + 0.01f * (le / (32.0f * 4096.0f));
  }
}

extern "C" void kernel_launch(void* const* d_in, const int* in_sizes, int n_in,
                              void* d_out, int out_size, void* d_ws, size_t ws_size,
                              hipStream_t stream) {
  const float* x  = (const float*)d_in[0];
  const float* W1 = (const float*)d_in[1];
  const float* b1 = (const float*)d_in[2];
  const float* w2 = (const float*)d_in[3];
  const float* b2 = (const float*)d_in[4];
  const int*   kp = (const int*)d_in[5];

  float* y = (float*)d_out;
  const size_t Y_ELEMS = (size_t)32 * 4097 * 256;   // 33,562,624
  float* aux    = y + Y_ELEMS;
  float* scores = aux + 1;
  float* probs  = scores + (size_t)32 * 4096;

  unsigned short* wt = (unsigned short*)d_ws;                 // 128 KB bf16 frag-major W1
  float* bg_ws = (float*)((char*)d_ws + 131072);              // 32x256 fp32
  float* sums  = bg_ws + 32 * 256;                            // 32 x {sum_p, sum_ent}

  hipMemsetAsync(bg_ws, 0, (32 * 256 + 64) * sizeof(float), stream);
  pack_w1<<<256, 256, 0, stream>>>(W1, wt);
  gater_main<<<4096, 128, 0, stream>>>(x, wt, b1, w2, b2, y, scores, probs, bg_ws, sums);
  finalize<<<32, 256, 0, stream>>>(bg_ws, sums, kp, y, aux);
}

// Round 4
// 315.107 us; speedup vs baseline: 1.1283x; 1.1283x over previous
//
#include <hip/hip_runtime.h>
#include <cstdint>

#define GEPS 1e-6f

typedef __attribute__((ext_vector_type(8))) short bf16x8;
typedef __attribute__((ext_vector_type(4))) float f32x4;

__device__ __forceinline__ unsigned short f2bf(float f) {
  unsigned int u = __float_as_uint(f);
  u += 0x7fffu + ((u >> 16) & 1u);
  return (unsigned short)(u >> 16);
}

// A&S 7.1.26 erf (|err| <= 1.5e-7) with native rcp/exp2. gelu exact form.
__device__ __forceinline__ float fast_gelu(float x) {
  float z  = x * 0.70710678118654752f;
  float az = fabsf(z);
  float t  = __builtin_amdgcn_rcpf(fmaf(0.3275911f, az, 1.0f));
  float poly = t * fmaf(t, fmaf(t, fmaf(t, fmaf(t, 1.061405429f, -1.453152027f),
                    1.421413741f), -0.284496736f), 0.254829592f);
  float e  = __builtin_amdgcn_exp2f(-az * az * 1.4426950408889634f);
  float ea = fmaf(-poly, e, 1.0f);
  float er = __uint_as_float(__float_as_uint(ea) | (__float_as_uint(z) & 0x80000000u));
  return 0.5f * x * (1.0f + er);
}

__device__ __forceinline__ float fast_sigmoid(float s) {
  return __builtin_amdgcn_rcpf(1.0f + __builtin_amdgcn_exp2f(-s * 1.4426950408889634f));
}

__device__ __forceinline__ float fast_log(float x) {
  return __builtin_amdgcn_logf(x) * 0.69314718055994531f;
}

// W1 [C=256][H=256] fp32 -> bf16 fragment-major, COALESCED WRITES.
// Output short index o = frag*512 + l*8 + j, frag = ht*8+kk (128 frags),
// l = q*16+tl, encodes B[k=kk*32+q*8+j][h=ht*16+tl].
// 8192 threads = 32 blocks x 256 thr, 8 shorts (one uint4) per thread.
__global__ __launch_bounds__(256) void pack_w1(const float* __restrict__ W1,
                                               unsigned short* __restrict__ wt) {
  int t = blockIdx.x * 256 + threadIdx.x;     // 0..8191
  int frag = t >> 6, l = t & 63;              // frag 0..127
  int ht = frag >> 3, kk = frag & 7, q = l >> 4, tl = l & 15;
  int h = ht * 16 + tl, k0 = kk * 32 + q * 8;
  unsigned int w[4];
  #pragma unroll
  for (int jj = 0; jj < 4; ++jj) {
    unsigned short lo = f2bf(W1[(k0 + 2 * jj) * 256 + h]);
    unsigned short hi = f2bf(W1[(k0 + 2 * jj + 1) * 256 + h]);
    w[jj] = (unsigned int)lo | ((unsigned int)hi << 16);
  }
  uint4* dst = (uint4*)(wt + (size_t)frag * 512 + l * 8);
  *dst = make_uint4(w[0], w[1], w[2], w[3]);
}

// Scores only: 2048 blocks x 256 thr, 64 tokens/block. Round-0-verified MFMA
// layout; LDS stride 260 shorts (conflict-free, measured r2).
__global__ __launch_bounds__(256) void score_kernel(
    const float* __restrict__ x, const unsigned short* __restrict__ wt,
    const float* __restrict__ b1, const float* __restrict__ w2,
    const float* __restrict__ b2,
    float* __restrict__ scores, float* __restrict__ probs, float* __restrict__ sums)
{
  __shared__ short A_lds[64 * 260];
  __shared__ float sc_lds[4][64];

  const int tid = threadIdx.x;
  const int tok0 = blockIdx.x * 64;
  const int b = tok0 >> 12;
  const float* xblk = x + (size_t)tok0 * 256;

  // stage x -> bf16 LDS; batches of 8 float4 loads kept in flight
  #pragma unroll
  for (int half = 0; half < 2; ++half) {
    float4 v[8];
    #pragma unroll
    for (int i = 0; i < 8; ++i)
      v[i] = *(const float4*)(xblk + (size_t)((half * 8 + i) * 256 + tid) * 4);
    #pragma unroll
    for (int i = 0; i < 8; ++i) {
      int f = (half * 8 + i) * 256 + tid;
      int token = f >> 6;
      int k4 = (f & 63) << 2;
      unsigned int lo = (unsigned int)f2bf(v[i].x) | ((unsigned int)f2bf(v[i].y) << 16);
      unsigned int hi = (unsigned int)f2bf(v[i].z) | ((unsigned int)f2bf(v[i].w) << 16);
      *(uint2*)&A_lds[token * 260 + k4] = make_uint2(lo, hi);
    }
  }
  __syncthreads();

  const int wave = tid >> 6, lane = tid & 63, tl = lane & 15, q = lane >> 4;

  f32x4 acc[4][4];
  #pragma unroll
  for (int mi = 0; mi < 4; ++mi)
    #pragma unroll
    for (int ni = 0; ni < 4; ++ni)
      acc[mi][ni] = (f32x4){0.f, 0.f, 0.f, 0.f};

  const bf16x8* wtv = (const bf16x8*)wt;
  #pragma unroll
  for (int kk = 0; kk < 8; ++kk) {
    bf16x8 a[4], bb[4];
    #pragma unroll
    for (int mi = 0; mi < 4; ++mi)
      a[mi] = *(const bf16x8*)&A_lds[(mi * 16 + tl) * 260 + kk * 32 + q * 8];
    #pragma unroll
    for (int ni = 0; ni < 4; ++ni)
      bb[ni] = wtv[((((wave << 2) + ni) << 3) + kk) * 64 + lane];
    #pragma unroll
    for (int mi = 0; mi < 4; ++mi)
      #pragma unroll
      for (int ni = 0; ni < 4; ++ni)
        acc[mi][ni] = __builtin_amdgcn_mfma_f32_16x16x32_bf16(a[mi], bb[ni], acc[mi][ni], 0, 0, 0);
  }

  float w2v[4], b1v[4];
  #pragma unroll
  for (int ni = 0; ni < 4; ++ni) {
    int h = wave * 64 + ni * 16 + tl;
    w2v[ni] = w2[h];
    b1v[ni] = b1[h];
  }
  #pragma unroll
  for (int mi = 0; mi < 4; ++mi) {
    #pragma unroll
    for (int r = 0; r < 4; ++r) {
      float s = 0.f;
      #pragma unroll
      for (int ni = 0; ni < 4; ++ni)
        s += fast_gelu(acc[mi][ni][r] + b1v[ni]) * w2v[ni];
      #pragma unroll
      for (int m = 1; m < 16; m <<= 1) s += __shfl_xor(s, m, 64);
      if (tl == 0) sc_lds[wave][mi * 16 + q * 4 + r] = s;
    }
  }
  __syncthreads();

  if (tid < 64) {
    float s = sc_lds[0][tid] + sc_lds[1][tid] + sc_lds[2][tid] + sc_lds[3][tid] + b2[0];
    float p = fast_sigmoid(s);
    size_t g = (size_t)tok0 + tid;
    scores[g] = s;
    probs[g] = p;
    float ent = -(p * fast_log(p + GEPS) + (1.0f - p) * fast_log(1.0f - p + GEPS));
    float sp = p, se = ent;
    #pragma unroll
    for (int m = 1; m < 64; m <<= 1) {
      sp += __shfl_xor(sp, m, 64);
      se += __shfl_xor(se, m, 64);
    }
    if (tid == 0) {
      atomicAdd(&sums[b * 2 + 0], sp);
      atomicAdd(&sums[b * 2 + 1], se);
    }
  }
}

// y = x*p + bg partials. 1024 blocks x 256 thr, 128 tokens/block, no atomics.
// Nontemporal y stores keep x resident in L3 for the re-read.
__global__ __launch_bounds__(256) void apply_kernel(
    const float* __restrict__ x, const float* __restrict__ probs,
    float* __restrict__ y, float* __restrict__ bg_scratch)
{
  __shared__ float p_lds[128];
  __shared__ float bg_lds[4][256];

  const int tid = threadIdx.x;
  const int b = blockIdx.x >> 5;
  const int chunk = blockIdx.x & 31;
  const float* xb = x + ((size_t)b * 4096 + chunk * 128) * 256;
  float* yb = y + ((size_t)b * 4097 + chunk * 128) * 256;

  if (tid < 128) p_lds[tid] = probs[b * 4096 + chunk * 128 + tid];
  __syncthreads();

  float4 bg = make_float4(0.f, 0.f, 0.f, 0.f);
  #pragma unroll 4
  for (int it = 0; it < 32; ++it) {
    int f = it * 256 + tid;             // float4 index in 128x256 tile
    int token = f >> 6;
    float4 xv = *(const float4*)(xb + (size_t)f * 4);
    float p = p_lds[token];
    f32x4 yv = {xv.x * p, xv.y * p, xv.z * p, xv.w * p};
    __builtin_nontemporal_store(yv, (f32x4*)(yb + (size_t)f * 4));
    float bw = 1.0f - p;
    bg.x += xv.x * bw; bg.y += xv.y * bw; bg.z += xv.z * bw; bg.w += xv.w * bw;
  }
  *(float4*)&bg_lds[tid >> 6][(tid & 63) << 2] = bg;
  __syncthreads();
  if (tid < 64) {
    int c = tid << 2;
    float4 v0 = *(const float4*)&bg_lds[0][c];
    float4 v1 = *(const float4*)&bg_lds[1][c];
    float4 v2 = *(const float4*)&bg_lds[2][c];
    float4 v3 = *(const float4*)&bg_lds[3][c];
    float4 r = make_float4(v0.x + v1.x + v2.x + v3.x, v0.y + v1.y + v2.y + v3.y,
                           v0.z + v1.z + v2.z + v3.z, v0.w + v1.w + v2.w + v3.w);
    *(float4*)(bg_scratch + (size_t)blockIdx.x * 256 + c) = r;
  }
}

__global__ __launch_bounds__(256) void finalize(
    const float* __restrict__ bg_scratch, const float* __restrict__ sums,
    const int* __restrict__ kp, float* __restrict__ y, float* __restrict__ aux)
{
  int b = blockIdx.x, c = threadIdx.x;
  float s = 0.f;
  #pragma unroll 8
  for (int chunk = 0; chunk < 32; ++chunk)
    s += bg_scratch[((size_t)(b * 32 + chunk)) * 256 + c];
  float sp = sums[b * 2 + 0];
  float denom = fmaxf(4096.0f - sp, GEPS);
  y[((size_t)b * 4097 + 4096) * 256 + c] = s / denom;
  if (b == 0 && c == 0) {
    float t = (float)kp[0] / 4096.0f;
    float lr = 0.f, le = 0.f;
    for (int i = 0; i < 32; ++i) {
      float r = sums[i * 2 + 0] / 4096.0f;
      lr += (r - t) * (r - t);
      le += sums[i * 2 + 1];
    }
    aux[0] = lr / 32.0f + 0.01f * (le / (32.0f * 4096.0f));
  }
}

extern "C" void kernel_launch(void* const* d_in, const int* in_sizes, int n_in,
                              void* d_out, int out_size, void* d_ws, size_t ws_size,
                              hipStream_t stream) {
  const float* x  = (const float*)d_in[0];
  const float* W1 = (const float*)d_in[1];
  const float* b1 = (const float*)d_in[2];
  const float* w2 = (const float*)d_in[3];
  const float* b2 = (const float*)d_in[4];
  const int*   kp = (const int*)d_in[5];

  float* y = (float*)d_out;
  const size_t Y_ELEMS = (size_t)32 * 4097 * 256;
  float* aux    = y + Y_ELEMS;
  float* scores = aux + 1;
  float* probs  = scores + (size_t)32 * 4096;

  unsigned short* wt = (unsigned short*)d_ws;                   // 128 KB
  float* sums       = (float*)((char*)d_ws + 131072);           // 64 floats
  float* bg_scratch = (float*)((char*)d_ws + 135168);           // 1024x256 fp32 = 1 MB

  hipMemsetAsync(sums, 0, 64 * sizeof(float), stream);
  pack_w1<<<32, 256, 0, stream>>>(W1, wt);
  score_kernel<<<2048, 256, 0, stream>>>(x, wt, b1, w2, b2, scores, probs, sums);
  apply_kernel<<<1024, 256, 0, stream>>>(x, probs, y, bg_scratch);
  finalize<<<32, 256, 0, stream>>>(bg_scratch, sums, kp, y, aux);
}